// Round 8
// baseline (101.645 us; speedup 1.0000x reference)
//
#include <hip/hip_runtime.h>

#define N 32768
#define P 8192
#define MX 8                          // x-values per wave (wave-uniform)
#define XG 2                          // x-groups per block
#define PH 2                          // pattern halves
#define THREADS (XG * PH * 64)        // 256
#define XPB (XG * MX)                 // 16 x per block
#define NBLK (N / XPB)                // 2048
#define PATS_PER_PH (P / PH)          // 4096 patterns per half
#define ITERS (PATS_PER_PH / 128)     // 32 chunks of 128 patterns (2/lane)

// f = log2(e)/(2*sigma^2), sigma^2 = 1.44; per-x |x|^2 cancels in num/den.
#define RBF_F 0.50093577808645257f

static __device__ __forceinline__ float fast_exp2(float x) {
#if __has_builtin(__builtin_amdgcn_exp2f)
    return __builtin_amdgcn_exp2f(x);
#else
    return exp2f(x);
#endif
}

// c[i] = { 2f*p0, 2f*p1, -f*|p|^2, w }
__global__ void prep_kernel(const float* __restrict__ pat,
                            const float* __restrict__ w2,
                            float4* __restrict__ c) {
    int i = blockIdx.x * blockDim.x + threadIdx.x;
    if (i < P) {
        float p0 = pat[2 * i];
        float p1 = pat[2 * i + 1];
        float4 v;
        v.x = 2.0f * RBF_F * p0;
        v.y = 2.0f * RBF_F * p1;
        v.z = -RBF_F * (p0 * p0 + p1 * p1);
        v.w = w2[i];
        c[i] = v;
    }
}

// (256, 8): request 8 blocks/CU residency (2nd arg = min waves/EU; for
// 256-thread blocks that equals blocks/CU). Constrains VGPR alloc to <=64.
__global__ __launch_bounds__(THREADS, 8) void
rbf_kernel(const float* __restrict__ X,
           const float4* __restrict__ c,
           float* __restrict__ out) {
    const int t    = threadIdx.x;
    const int lane = t & 63;
    const int w    = __builtin_amdgcn_readfirstlane(t >> 6);  // 0..3
    const int xg   = w >> 1;
    const int ph   = w & 1;

    // 8 wave-uniform x-values (held in SGPRs by the compiler)
    const int xb = blockIdx.x * XPB + xg * MX;
    const float2* Xp = (const float2*)X;
    float x0[MX], x1[MX];
#pragma unroll
    for (int i = 0; i < MX; ++i) {
        float2 xv = Xp[xb + i];
        x0[i] = xv.x;
        x1[i] = xv.y;
    }

    float num[MX], den[MX];
#pragma unroll
    for (int i = 0; i < MX; ++i) { num[i] = 0.f; den[i] = 0.f; }

    // this wave's pattern stream: chunk j = 128 patterns, 2 per lane
    const float4* __restrict__ C4 = c + (size_t)ph * PATS_PER_PH;

    auto compute = [&](const float4& A, const float4& B) {
#pragma unroll
        for (int i = 0; i < MX; ++i) {
            float ta = fmaf(A.y, x1[i], fmaf(A.x, x0[i], A.z));
            float tb = fmaf(B.y, x1[i], fmaf(B.x, x0[i], B.z));
            float ka = fast_exp2(ta);
            float kb = fast_exp2(tb);
            den[i] += ka;
            num[i] = fmaf(ka, A.w, num[i]);
            den[i] += kb;
            num[i] = fmaf(kb, B.w, num[i]);
        }
    };

    // depth-2 software pipeline, hand-unrolled x2 (SSA renaming, no copies)
    float4 a0 = C4[(0 << 7) + 2 * lane];
    float4 b0 = C4[(0 << 7) + 2 * lane + 1];
    float4 a1 = C4[(1 << 7) + 2 * lane];
    float4 b1 = C4[(1 << 7) + 2 * lane + 1];

    for (int j = 0; j < ITERS; j += 2) {
        {
            const int j2 = (j + 2) & (ITERS - 1);
            float4 na = C4[(j2 << 7) + 2 * lane];
            float4 nb = C4[(j2 << 7) + 2 * lane + 1];
            compute(a0, b0);
            a0 = na; b0 = nb;
        }
        {
            const int j3 = (j + 3) & (ITERS - 1);
            float4 na = C4[(j3 << 7) + 2 * lane];
            float4 nb = C4[(j3 << 7) + 2 * lane + 1];
            compute(a1, b1);
            a1 = na; b1 = nb;
        }
    }

    // 6-step butterfly reduction across the wave (pattern partials)
#pragma unroll
    for (int m = 1; m < 64; m <<= 1) {
#pragma unroll
        for (int i = 0; i < MX; ++i) {
            num[i] += __shfl_xor(num[i], m, 64);
            den[i] += __shfl_xor(den[i], m, 64);
        }
    }

    __shared__ float red[XG][PH][MX][2];
    if (lane == 0) {
#pragma unroll
        for (int i = 0; i < MX; ++i) {
            red[xg][ph][i][0] = num[i];
            red[xg][ph][i][1] = den[i];
        }
    }
    __syncthreads();

    if (t < XPB) {
        int g = t >> 3, xi = t & 7;
        float nn = red[g][0][xi][0] + red[g][1][xi][0];
        float dd = red[g][0][xi][1] + red[g][1][xi][1];
        out[blockIdx.x * XPB + t] = nn / dd;
    }
}

extern "C" void kernel_launch(void* const* d_in, const int* in_sizes, int n_in,
                              void* d_out, int out_size, void* d_ws, size_t ws_size,
                              hipStream_t stream) {
    const float* X   = (const float*)d_in[0];   // [32768, 2]
    const float* pat = (const float*)d_in[1];   // [8192, 2]
    const float* w2  = (const float*)d_in[2];   // [8192]
    float* out = (float*)d_out;                 // [32768]
    float4* c = (float4*)d_ws;                  // 8192 * 16 B = 128 KB

    prep_kernel<<<(P + 255) / 256, 256, 0, stream>>>(pat, w2, c);
    rbf_kernel<<<NBLK, THREADS, 0, stream>>>(X, c, out);
}